// Round 2
// baseline (448.429 us; speedup 1.0000x reference)
//
#include <hip/hip_runtime.h>

typedef unsigned short u16;
typedef __attribute__((ext_vector_type(4))) float f32x4;
typedef __attribute__((ext_vector_type(8))) __bf16 bf16x8;

// ---------- helpers ----------
__device__ __forceinline__ u16 f2bf(float f) {
    unsigned int x = __float_as_uint(f);
    x += 0x7fffu + ((x >> 16) & 1u);          // RNE
    return (u16)(x >> 16);
}
__device__ __forceinline__ float bf2f(u16 u) {
    return __uint_as_float(((unsigned int)u) << 16);
}
__device__ __forceinline__ void async16(const void* g, void* l) {
    __builtin_amdgcn_global_load_lds(
        (const __attribute__((address_space(1))) void*)g,
        (__attribute__((address_space(3))) void*)l,
        16, 0, 0);
}

// ---------- fp32 -> bf16 convert ----------
__global__ __launch_bounds__(256)
void cvt_f2b(const float* __restrict__ in, u16* __restrict__ out, int n)
{
    const int i = (blockIdx.x * 256 + threadIdx.x) * 4;
    if (i < n) {
        const float4 v = *(const float4*)(in + i);
        ushort4 o;
        o.x = f2bf(v.x); o.y = f2bf(v.y); o.z = f2bf(v.z); o.w = f2bf(v.w);
        *(ushort4*)(out + i) = o;
    }
}

// ---------- GEMM: C = A[M,K] * B[N,K]^T, bf16 in, fp32 acc ------------------
// MODE 0: plain fp32 C write (ldc = N)
// MODE 1: QKV epilogue (bf16): cols <2560 -> qkv[row*3072+col]; cols >=2560 ->
//         vbuf (V stored transposed: vbuf[((b*4+kvh)*128+d)*2048 + t])
template <int MODE>
__global__ __launch_bounds__(256)
void gemm_bt(const u16* __restrict__ A,
             const u16* __restrict__ B0,
             const u16* __restrict__ B1,
             u16* __restrict__ C,
             float* __restrict__ Cf,
             u16* __restrict__ vbuf,
             int M, int N, int K)
{
    __shared__ __align__(16) u16 As[128 * 32];
    __shared__ __align__(16) u16 Bs[128 * 32];

    const int tid  = threadIdx.x;
    const int w    = tid >> 6;
    const int lane = tid & 63;
    const int fl   = lane & 15;
    const int q4   = lane >> 4;
    const int m0   = blockIdx.y * 128;
    const int n0   = blockIdx.x * 128;
    const int wr   = w >> 1, wc = w & 1;

    const u16* Bp = B0;
    int nb = n0;
    if (MODE == 1 && n0 >= 2048) { Bp = B1; nb = n0 - 2048; }

    const int srow = lane >> 2;          // 0..15
    const int scol = (lane & 3) << 3;    // 0,8,16,24
    const u16* ag = A  + (size_t)(m0 + w * 32 + srow) * K + scol;
    const u16* bg = Bp + (size_t)(nb + w * 32 + srow) * K + scol;
    u16* al = &As[(w * 32) * 32];
    u16* bl = &Bs[(w * 32) * 32];

    f32x4 acc[4][4];
    for (int i = 0; i < 4; ++i)
        for (int j = 0; j < 4; ++j)
            acc[i][j] = f32x4{0.f, 0.f, 0.f, 0.f};

    for (int kt = 0; kt < K; kt += 32) {
        __syncthreads();
        async16(ag + kt,                    al);
        async16(ag + kt + (size_t)16 * K,   al + 16 * 32);
        async16(bg + kt,                    bl);
        async16(bg + kt + (size_t)16 * K,   bl + 16 * 32);
        __syncthreads();

        bf16x8 af[4], bfr[4];
        #pragma unroll
        for (int t = 0; t < 4; ++t) {
            af[t]  = *(const bf16x8*)&As[(wr * 64 + t * 16 + fl) * 32 + q4 * 8];
            bfr[t] = *(const bf16x8*)&Bs[(wc * 64 + t * 16 + fl) * 32 + q4 * 8];
        }
        #pragma unroll
        for (int mt = 0; mt < 4; ++mt)
            #pragma unroll
            for (int nt = 0; nt < 4; ++nt)
                acc[mt][nt] = __builtin_amdgcn_mfma_f32_16x16x32_bf16(
                    af[mt], bfr[nt], acc[mt][nt], 0, 0, 0);
    }

    #pragma unroll
    for (int mt = 0; mt < 4; ++mt) {
        #pragma unroll
        for (int nt = 0; nt < 4; ++nt) {
            const int colb = n0 + wc * 64 + nt * 16 + fl;
            #pragma unroll
            for (int r = 0; r < 4; ++r) {
                const int row = m0 + wr * 64 + mt * 16 + q4 * 4 + r;
                if (MODE == 0) {
                    Cf[(size_t)row * N + colb] = acc[mt][nt][r];
                } else {
                    const u16 val = f2bf(acc[mt][nt][r]);
                    if (colb < 2560) {
                        C[(size_t)row * 3072 + colb] = val;
                    } else {
                        const int f  = colb - 2560;
                        const int t  = row & 2047;
                        const int bb = row >> 11;
                        vbuf[((size_t)((bb << 2) + (f >> 7)) * 128 + (f & 127)) * 2048 + t] = val;
                    }
                }
            }
        }
    }
}

// ---------- RoPE (in place on qkv: q cols [0,2048), k cols [2048,2560)) -----
__global__ __launch_bounds__(256)
void rope_kernel(u16* __restrict__ qkv)
{
    const int idx = blockIdx.x * 256 + threadIdx.x;   // [0, 4096*20*64)
    const int i   = idx & 63;                          // freq index
    const int t1  = idx >> 6;
    const int hh  = t1 % 20;                           // 0..15 q-heads, 16..19 k-heads
    const int m   = t1 / 20;                           // row in [0,4096)
    const int pos = m & 2047;
    const int col = (hh < 16) ? (hh << 7) : (2048 + ((hh - 16) << 7));
    u16* p = qkv + (size_t)m * 3072 + col;

    const float inv = powf(10000.0f, -(float)(2 * i) * (1.0f / 128.0f));
    const float ang = (float)pos * inv;
    float s, c;
    sincosf(ang, &s, &c);
    const float x1 = bf2f(p[i]);
    const float x2 = bf2f(p[i + 64]);
    p[i]      = f2bf(x1 * c - x2 * s);
    p[i + 64] = f2bf(x2 * c + x1 * s);
}

// ---------- causal flash attention -----------------------------------------
// grid: (T/64, B*H); block 256 = 4 waves, each wave owns 16 q-rows.
__global__ __launch_bounds__(256)
void attn_kernel(const u16* __restrict__ qkv,
                 const u16* __restrict__ vbuf,
                 u16* __restrict__ y)
{
    constexpr int T = 2048;
    const int qi  = blockIdx.x;       // q tile 0..31
    const int bh  = blockIdx.y;       // 0..31
    const int b   = bh >> 4;
    const int h   = bh & 15;
    const int kvh = h >> 2;

    const int tid  = threadIdx.x;
    const int w    = tid >> 6;
    const int lane = tid & 63;
    const int fl   = lane & 15;
    const int q4   = lane >> 4;

    __shared__ __align__(16) u16 Qs[64 * 136];
    __shared__ __align__(16) u16 Ks[64 * 136];
    __shared__ __align__(16) u16 Vt[128 * 72];   // [d][kv]
    __shared__ __align__(16) u16 Ps[64 * 72];

    const u16* Qg = qkv  + (size_t)(b * T) * 3072 + (h << 7);
    const u16* Kg = qkv  + (size_t)(b * T) * 3072 + 2048 + (kvh << 7);
    const u16* Vg = vbuf + (size_t)((b * 4 + kvh) * 128) * T;

    // stage Q tile once: rows qi*64..+64, 128 cols
    #pragma unroll
    for (int it = 0; it < 4; ++it) {
        const int cc = tid + it * 256;
        const int row = cc >> 4, colc = cc & 15;
        uint4 d = *(const uint4*)&Qg[(size_t)(qi * 64 + row) * 3072 + colc * 8];
        *(uint4*)&Qs[row * 136 + colc * 8] = d;
    }

    float mrow[4], lrow[4];
    f32x4 o[8];
    #pragma unroll
    for (int r = 0; r < 4; ++r) { mrow[r] = -1e30f; lrow[r] = 0.f; }
    #pragma unroll
    for (int dt = 0; dt < 8; ++dt) o[dt] = f32x4{0.f, 0.f, 0.f, 0.f};

    const float scale = 0.08838834764831845f;   // 1/sqrt(128)

    for (int j = 0; j <= qi; ++j) {
        __syncthreads();
        // stage K tile [64][128] and V tile transposed [128][64]
        #pragma unroll
        for (int it = 0; it < 4; ++it) {
            const int cc = tid + it * 256;
            const int row = cc >> 4, colc = cc & 15;
            uint4 d = *(const uint4*)&Kg[(size_t)(j * 64 + row) * 3072 + colc * 8];
            *(uint4*)&Ks[row * 136 + colc * 8] = d;
        }
        #pragma unroll
        for (int it = 0; it < 4; ++it) {
            const int cc = tid + it * 256;
            const int dr = cc >> 3, colc = cc & 7;
            uint4 d = *(const uint4*)&Vg[(size_t)dr * T + j * 64 + colc * 8];
            *(uint4*)&Vt[dr * 72 + colc * 8] = d;
        }
        __syncthreads();

        // S = Q K^T  (wave's 16 q-rows x 64 kv)
        f32x4 sacc[4];
        #pragma unroll
        for (int nt = 0; nt < 4; ++nt) sacc[nt] = f32x4{0.f, 0.f, 0.f, 0.f};
        #pragma unroll
        for (int kc = 0; kc < 4; ++kc) {
            bf16x8 aq = *(const bf16x8*)&Qs[(w * 16 + fl) * 136 + kc * 32 + q4 * 8];
            #pragma unroll
            for (int nt = 0; nt < 4; ++nt) {
                bf16x8 bk = *(const bf16x8*)&Ks[(nt * 16 + fl) * 136 + kc * 32 + q4 * 8];
                sacc[nt] = __builtin_amdgcn_mfma_f32_16x16x32_bf16(aq, bk, sacc[nt], 0, 0, 0);
            }
        }

        // scale + causal mask (only diagonal tile needs it)
        float sv[4][4];
        #pragma unroll
        for (int nt = 0; nt < 4; ++nt)
            #pragma unroll
            for (int r = 0; r < 4; ++r) {
                float v = sacc[nt][r] * scale;
                if (j == qi) {
                    const int kvidx = nt * 16 + fl;
                    const int qidx  = w * 16 + q4 * 4 + r;
                    if (kvidx > qidx) v = -1e30f;
                }
                sv[nt][r] = v;
            }

        // online softmax: row reductions across the 16-lane group holding a row
        float alpha[4], rsum[4];
        #pragma unroll
        for (int r = 0; r < 4; ++r) {
            float mx = fmaxf(fmaxf(sv[0][r], sv[1][r]), fmaxf(sv[2][r], sv[3][r]));
            #pragma unroll
            for (int off = 1; off < 16; off <<= 1)
                mx = fmaxf(mx, __shfl_xor(mx, off, 64));
            const float mn = fmaxf(mrow[r], mx);
            alpha[r] = __expf(mrow[r] - mn);
            mrow[r]  = mn;
            rsum[r]  = 0.f;
        }
        #pragma unroll
        for (int nt = 0; nt < 4; ++nt)
            #pragma unroll
            for (int r = 0; r < 4; ++r) {
                const float p = __expf(sv[nt][r] - mrow[r]);
                rsum[r] += p;
                Ps[(w * 16 + q4 * 4 + r) * 72 + nt * 16 + fl] = f2bf(p);
            }
        #pragma unroll
        for (int r = 0; r < 4; ++r) {
            float s_ = rsum[r];
            #pragma unroll
            for (int off = 1; off < 16; off <<= 1)
                s_ += __shfl_xor(s_, off, 64);
            lrow[r] = lrow[r] * alpha[r] + s_;
        }
        #pragma unroll
        for (int dt = 0; dt < 8; ++dt)
            #pragma unroll
            for (int r = 0; r < 4; ++r)
                o[dt][r] *= alpha[r];

        // make P writes visible to the whole wave before fragment reads
        asm volatile("s_waitcnt lgkmcnt(0)" ::: "memory");

        // O += P V
        #pragma unroll
        for (int kc = 0; kc < 2; ++kc) {
            bf16x8 ap = *(const bf16x8*)&Ps[(w * 16 + fl) * 72 + kc * 32 + q4 * 8];
            #pragma unroll
            for (int dt = 0; dt < 8; ++dt) {
                bf16x8 bv = *(const bf16x8*)&Vt[(dt * 16 + fl) * 72 + kc * 32 + q4 * 8];
                o[dt] = __builtin_amdgcn_mfma_f32_16x16x32_bf16(ap, bv, o[dt], 0, 0, 0);
            }
        }
    }

    // normalize + write y[b*T+t][h*128+d]  (bf16 workspace)
    #pragma unroll
    for (int r = 0; r < 4; ++r) lrow[r] = 1.0f / lrow[r];
    #pragma unroll
    for (int dt = 0; dt < 8; ++dt)
        #pragma unroll
        for (int r = 0; r < 4; ++r) {
            const int row = qi * 64 + w * 16 + q4 * 4 + r;
            y[(size_t)(b * T + row) * 2048 + (h << 7) + dt * 16 + fl] =
                f2bf(o[dt][r] * lrow[r]);
        }
}

// ---------- launch ----------------------------------------------------------
extern "C" void kernel_launch(void* const* d_in, const int* in_sizes, int n_in,
                              void* d_out, int out_size, void* d_ws, size_t ws_size,
                              hipStream_t stream)
{
    const float* x   = (const float*)d_in[0];   // [4096, 2048] fp32
    const float* Wq  = (const float*)d_in[1];   // [2048, 2048] fp32
    const float* Wkv = (const float*)d_in[2];   // [1024, 2048] fp32
    const float* Wo  = (const float*)d_in[3];   // [2048, 2048] fp32
    float* out = (float*)d_out;                 // [4096, 2048] fp32

    const int nx = 4096 * 2048, nq = 2048 * 2048, nkv = 1024 * 2048, no = 2048 * 2048;

    u16* xb   = (u16*)d_ws;                          // bf16 copies
    u16* wqb  = xb  + nx;
    u16* wkvb = wqb + nq;
    u16* wob  = wkvb + nkv;
    u16* qkv  = wob + no;                            // [4096, 3072]
    u16* vbuf = qkv + (size_t)4096 * 3072;           // V^T [B*KV*128, 2048]
    u16* y    = vbuf + (size_t)2 * 4 * 128 * 2048;   // [4096, 2048]

    cvt_f2b<<<nx  / 1024, 256, 0, stream>>>(x,   xb,   nx);
    cvt_f2b<<<nq  / 1024, 256, 0, stream>>>(Wq,  wqb,  nq);
    cvt_f2b<<<nkv / 1024, 256, 0, stream>>>(Wkv, wkvb, nkv);
    cvt_f2b<<<no  / 1024, 256, 0, stream>>>(Wo,  wob,  no);

    dim3 g1(3072 / 128, 4096 / 128);
    gemm_bt<1><<<g1, 256, 0, stream>>>(xb, wqb, wkvb, qkv, nullptr, vbuf, 4096, 3072, 2048);

    rope_kernel<<<(4096 * 20 * 64) / 256, 256, 0, stream>>>(qkv);

    attn_kernel<<<dim3(32, 32), 256, 0, stream>>>(qkv, vbuf, y);

    dim3 g2(2048 / 128, 4096 / 128);
    gemm_bt<0><<<g2, 256, 0, stream>>>(y, wob, nullptr, nullptr, out, nullptr, 4096, 2048, 2048);
}